// Round 9
// baseline (236.886 us; speedup 1.0000x reference)
//
#include <hip/hip_runtime.h>

#define EPSV 1e-5f

// ---------------- KP: 4x4 avg-pool, one block per (b,c) channel-map ----------------
// grid 5120 = 16*320, block 256 (one thread per pooled cell).
// Each thread: 4 independent float4 loads -> pooled value; block reduces
// per-channel (S, SS) into pcs[b*320+c]. ~20 blocks/CU -> BW-bound, not
// latency-bound (the old fused kernel ran 1 block/CU at 907 GB/s).
__global__ __launch_bounds__(256) void kp_pool(
    const float* __restrict__ x, float* __restrict__ pooled, float2* __restrict__ pcs)
{
    const int bc = blockIdx.x;                          // b*320 + c
    const int t = threadIdx.x;

    const float* base = x + (((size_t)bc) * 64 + (t >> 4) * 4) * 64 + (t & 15) * 4;
    float acc = 0.f;
#pragma unroll
    for (int i = 0; i < 4; ++i) {
        const float4 r = *reinterpret_cast<const float4*>(base + i * 64);
        acc += r.x + r.y + r.z + r.w;
    }
    const float v = acc * (1.f / 16.f);
    pooled[(size_t)bc * 256 + t] = v;

    float s = v, ss = v * v;
    __shared__ float rs[4], rss[4];
#pragma unroll
    for (int off = 32; off; off >>= 1) {
        s += __shfl_down(s, off);
        ss += __shfl_down(ss, off);
    }
    const int wid = t >> 6, lane = t & 63;
    if (lane == 0) { rs[wid] = s; rss[wid] = ss; }
    __syncthreads();
    if (t == 0)
        pcs[bc] = make_float2(rs[0] + rs[1] + rs[2] + rs[3],
                              rss[0] + rss[1] + rss[2] + rss[3]);
}

// ---------------- KC: GroupNorm(32) + SiLU + conv3x3 320->8, chunked over channels ----------------
// grid 266 = B(16) x chunks(16) + 10 combo-precompute blocks, block 256.
// Group stats from per-channel partials (10 uniform float2 loads per group).
// Pooled data is L2/L3-resident (5.2 MB). Writes partials z0p[b][ch][8][256].
__global__ __launch_bounds__(256) void kc_gn_conv(
    const float* __restrict__ pooled, const float2* __restrict__ pcs,
    const float* __restrict__ g1, const float* __restrict__ b1,
    const float* __restrict__ w1, float* __restrict__ z0p,
    const float* __restrict__ w2, float* __restrict__ cmb)
{
    const int blk = blockIdx.x;
    const int t = threadIdx.x;

    if (blk >= 256) {
        // ---- combo precompute for k4: one thread per (o,c) pair ----
        const int idx = (blk - 256) * 256 + t;          // 0..2559 = 320*8
        const float* k = w2 + idx * 9;                  // (o*8+c)*9
        const float k0 = k[0], k1 = k[1], k2 = k[2];
        const float k3 = k[3], k4 = k[4], k5 = k[5];
        const float k6 = k[6], k7 = k[7], k8 = k[8];

        const float q12x = k3 + k6, q12y = k4 + k7, q12z = k5 + k8;
        const float q01x = k0 + k3, q01y = k1 + k4, q01z = k2 + k5;
        const float qax = q12x + k0, qay = q12y + k1, qaz = q12z + k2;

        const float r0_c12 = k1 + k2,      r0_c012 = r0_c12 + k0,     r0_c01 = k0 + k1;
        const float q12_c12 = q12y + q12z, q12_c012 = q12_c12 + q12x, q12_c01 = q12x + q12y;
        const float qa_c12 = qay + qaz,    qa_c012 = qa_c12 + qax,    qa_c01 = qax + qay;
        const float q01_c12 = q01y + q01z, q01_c012 = q01_c12 + q01x, q01_c01 = q01x + q01y;
        const float r2_c12 = k7 + k8,      r2_c012 = r2_c12 + k6,     r2_c01 = k6 + k7;

        float* d = cmb + idx * 25;
        d[0] = k0;        d[1] = r0_c12;   d[2] = q12x;     d[3] = q12_c12;
        d[4] = r0_c012;   d[5] = q12_c012;
        d[6] = r0_c01;    d[7] = k2;       d[8] = q12_c01;  d[9] = q12z;
        d[10] = qax;      d[11] = qa_c12;
        d[12] = qa_c012;
        d[13] = qa_c01;   d[14] = qaz;
        d[15] = q01x;     d[16] = q01_c12; d[17] = k6;      d[18] = r2_c12;
        d[19] = q01_c012; d[20] = r2_c012;
        d[21] = q01_c01;  d[22] = q01z;    d[23] = r2_c01;  d[24] = k8;
        return;
    }

    const int b = blk >> 4, ch = blk & 15;
    const int ph = t >> 4, pw = t & 15;
    const int c0 = ch * 20;

    __shared__ __align__(16) float tiles[20 * 256];
    __shared__ float lw[8 * 20 * 9];

    for (int i = t; i < 1440; i += 256) {
        const int o = i / 180, rem = i % 180, cc = rem / 9, k = rem % 9;
        lw[i] = w1[(o * 320 + c0 + cc) * 9 + k];
    }

    // group stats (groups 2ch, 2ch+1) from per-channel partial sums
    float mean[2], inv[2];
#pragma unroll
    for (int g = 0; g < 2; ++g) {
        float S = 0.f, SS = 0.f;
#pragma unroll
        for (int j = 0; j < 10; ++j) {
            const float2 p = pcs[b * 320 + c0 + g * 10 + j];
            S += p.x; SS += p.y;
        }
        mean[g] = S * (1.f / 2560.f);
        const float var = SS * (1.f / 2560.f) - mean[g] * mean[g];
        inv[g] = rsqrtf(var + EPSV);
    }

    // GN + SiLU straight into the conv tile
#pragma unroll
    for (int k = 0; k < 20; ++k) {
        const int c = c0 + k, g = k / 10;
        const float val = pooled[(size_t)(b * 320 + c) * 256 + t];
        const float xn = (val - mean[g]) * inv[g] * g1[c] + b1[c];
        tiles[k * 256 + t] = xn / (1.f + __expf(-xn));
    }
    __syncthreads();

    // conv3x3 over the 20 staged channels
    float acc[8] = {0.f, 0.f, 0.f, 0.f, 0.f, 0.f, 0.f, 0.f};
    for (int cc = 0; cc < 20; ++cc) {
        const float* tp = &tiles[cc * 256];
#pragma unroll
        for (int ky = 0; ky < 3; ++ky) {
            const int yy = ph + ky - 1;
            if ((unsigned)yy > 15u) continue;
#pragma unroll
            for (int kx = 0; kx < 3; ++kx) {
                const int xx = pw + kx - 1;
                if ((unsigned)xx > 15u) continue;
                const float val = tp[yy * 16 + xx];
                const int wi = cc * 9 + ky * 3 + kx;
#pragma unroll
                for (int o = 0; o < 8; ++o) acc[o] += lw[o * 180 + wi] * val;
            }
        }
    }
    float* zp = z0p + (size_t)blk * 2048 + t;   // [b][ch][o][t]
#pragma unroll
    for (int o = 0; o < 8; ++o) zp[o * 256] = acc[o];
}

// ---------------- K3A: reduce partials -> GN(8) -> per-head qkv -> attention ----------------
// grid 64 = B(16) x H(4), block 256 (one thread per pixel n).
__global__ __launch_bounds__(256) void k3a_attn(
    const float* __restrict__ z0p, const float* __restrict__ b_conv1,
    const float* __restrict__ ga, const float* __restrict__ ba,
    const float* __restrict__ w_qkv, const float* __restrict__ b_qkv,
    float* __restrict__ z0, float* __restrict__ aout)
{
    const int blk = blockIdx.x;
    const int b = blk >> 2, h = blk & 3;
    const int t = threadIdx.x;
    const int wid = t >> 6, lane = t & 63;

    __shared__ float zsh[8][256];
    __shared__ float stats[16];
    __shared__ float4 kvs[256];

    // reduce 16 chunk-partials + bias
    float zc[8];
#pragma unroll
    for (int c = 0; c < 8; ++c) zc[c] = b_conv1[c];
    for (int ch = 0; ch < 16; ++ch) {
        const float* pp = z0p + ((size_t)(b * 16 + ch)) * 2048 + t;
#pragma unroll
        for (int c = 0; c < 8; ++c) zc[c] += pp[c * 256];
    }
#pragma unroll
    for (int c = 0; c < 8; ++c) zsh[c][t] = zc[c];
    if (h == 0) {
#pragma unroll
        for (int c = 0; c < 8; ++c) z0[(size_t)b * 2048 + c * 256 + t] = zc[c];
    }
    __syncthreads();

    // GN(8) stats: 2 channels per wave
#pragma unroll
    for (int cc = 0; cc < 2; ++cc) {
        const int c = wid * 2 + cc;
        const float a0 = zsh[c][lane], a1v = zsh[c][lane + 64], a2v = zsh[c][lane + 128], a3v = zsh[c][lane + 192];
        float s = a0 + a1v + a2v + a3v;
        float ss = a0 * a0 + a1v * a1v + a2v * a2v + a3v * a3v;
#pragma unroll
        for (int off = 32; off; off >>= 1) {
            s += __shfl_down(s, off);
            ss += __shfl_down(ss, off);
        }
        if (lane == 0) {
            const float m = s * (1.f / 256.f);
            const float vv = ss * (1.f / 256.f) - m * m;
            stats[2 * c] = m;
            stats[2 * c + 1] = rsqrtf(vv + EPSV);
        }
    }
    __syncthreads();

    // per-head qkv: rows {2h, 2h+1} (q), {8+2h, 9+2h} (k), {16+2h, 17+2h} (v)
    float gn[8];
#pragma unroll
    for (int c = 0; c < 8; ++c) gn[c] = (zsh[c][t] - stats[2 * c]) * stats[2 * c + 1] * ga[c] + ba[c];

    float pr[6];
    const int rows[6] = {2 * h, 2 * h + 1, 8 + 2 * h, 9 + 2 * h, 16 + 2 * h, 17 + 2 * h};
#pragma unroll
    for (int j = 0; j < 6; ++j) {
        const int o = rows[j];
        float acc = b_qkv[o];
#pragma unroll
        for (int c = 0; c < 8; ++c) acc += w_qkv[o * 8 + c] * gn[c];
        pr[j] = acc;
    }
    // q pre-scaled by dh^-0.5 * log2(e) so attention inner loop is dot+exp2
    const float lscale = 0.70710678118654752f * 1.44269504088896341f;
    const float qx = pr[0] * lscale, qy = pr[1] * lscale;
    kvs[t] = make_float4(pr[2], pr[3], pr[4], pr[5]);
    __syncthreads();

    // attention (max-free softmax; scores bounded |s|<~3), uniform LDS broadcast
    float l = 0.f, o0 = 0.f, o1 = 0.f;
#pragma unroll 16
    for (int m = 0; m < 256; ++m) {
        const float4 kvv = kvs[m];
        const float e = __builtin_exp2f(qx * kvv.x + qy * kvv.y);
        l += e;
        o0 += e * kvv.z;
        o1 += e * kvv.w;
    }
    const float rl = 1.f / l;
    aout[(size_t)b * 2048 + t * 8 + 2 * h]     = o0 * rl;
    aout[(size_t)b * 2048 + t * 8 + 2 * h + 1] = o1 * rl;
}

// ---------------- K3C: proj+res, LN, MLP+res, GN2 stats (pre-upsample) + SiLU ----------------
// grid 16 = B, block 256 (one thread per pixel n)
__global__ __launch_bounds__(256) void k3c_post(
    const float* __restrict__ z0, const float* __restrict__ aout,
    const float* __restrict__ w_proj, const float* __restrict__ b_proj,
    const float* __restrict__ ln_g, const float* __restrict__ ln_b,
    const float* __restrict__ w_fc1, const float* __restrict__ b_fc1,
    const float* __restrict__ w_fc2, const float* __restrict__ b_fc2,
    const float* __restrict__ g2, const float* __restrict__ b2,
    float* __restrict__ a2)
{
    const int b = blockIdx.x, t = threadIdx.x;
    const int wid = t >> 6, lane = t & 63;

    __shared__ float zsh[8][256];
    __shared__ float stats[16];

#pragma unroll
    for (int c = 0; c < 8; ++c) zsh[c][t] = z0[(size_t)b * 2048 + c * 256 + t];

    // per-pixel attention output (8 contiguous floats)
    const float4 ao0 = *reinterpret_cast<const float4*>(aout + (size_t)b * 2048 + t * 8);
    const float4 ao1 = *reinterpret_cast<const float4*>(aout + (size_t)b * 2048 + t * 8 + 4);
    const float ao[8] = {ao0.x, ao0.y, ao0.z, ao0.w, ao1.x, ao1.y, ao1.z, ao1.w};
    __syncthreads();

    // proj + residual
    float z1[8];
#pragma unroll
    for (int o = 0; o < 8; ++o) {
        float acc = b_proj[o];
#pragma unroll
        for (int c = 0; c < 8; ++c) acc += w_proj[o * 8 + c] * ao[c];
        z1[o] = zsh[o][t] + acc;
    }

    // LayerNorm over 8 channels (per pixel)
    float mu = 0.f;
#pragma unroll
    for (int c = 0; c < 8; ++c) mu += z1[c];
    mu *= (1.f / 8.f);
    float var = 0.f;
#pragma unroll
    for (int c = 0; c < 8; ++c) { const float d = z1[c] - mu; var += d * d; }
    var *= (1.f / 8.f);
    const float linv = rsqrtf(var + EPSV);
    float ln[8];
#pragma unroll
    for (int c = 0; c < 8; ++c) ln[c] = (z1[c] - mu) * linv * ln_g[c] + ln_b[c];

    // fc1 + exact gelu
    float hg[16];
#pragma unroll
    for (int o = 0; o < 16; ++o) {
        float hv = b_fc1[o];
#pragma unroll
        for (int c = 0; c < 8; ++c) hv += w_fc1[o * 8 + c] * ln[c];
        hg[o] = 0.5f * hv * (1.f + erff(hv * 0.70710678f));
    }
    // fc2 + residual
    float z2[8];
#pragma unroll
    for (int c = 0; c < 8; ++c) {
        float acc = b_fc2[c];
#pragma unroll
        for (int o = 0; o < 16; ++o) acc += w_fc2[c * 16 + o] * hg[o];
        z2[c] = z1[c] + acc;
    }

    // GN2 stats on pre-upsample map (repeat preserves mean/var), then SiLU
    __syncthreads();
#pragma unroll
    for (int c = 0; c < 8; ++c) zsh[c][t] = z2[c];
    __syncthreads();
#pragma unroll
    for (int cc = 0; cc < 2; ++cc) {
        const int c = wid * 2 + cc;
        const float a0 = zsh[c][lane], a1v = zsh[c][lane + 64], a2v = zsh[c][lane + 128], a3v = zsh[c][lane + 192];
        float s = a0 + a1v + a2v + a3v;
        float ss = a0 * a0 + a1v * a1v + a2v * a2v + a3v * a3v;
#pragma unroll
        for (int off = 32; off; off >>= 1) {
            s += __shfl_down(s, off);
            ss += __shfl_down(ss, off);
        }
        if (lane == 0) {
            const float m = s * (1.f / 256.f);
            const float vv = ss * (1.f / 256.f) - m * m;
            stats[2 * c] = m;
            stats[2 * c + 1] = rsqrtf(vv + EPSV);
        }
    }
    __syncthreads();
#pragma unroll
    for (int c = 0; c < 8; ++c) {
        const float xn = (z2[c] - stats[2 * c]) * stats[2 * c + 1] * g2[c] + b2[c];
        a2[(size_t)b * 2048 + c * 256 + t] = xn / (1.f + __expf(-xn));
    }
}

// ---------------- K4: upsample-on-the-fly conv3x3 8->320 on 64x64 ----------------
// Combo weights precomputed per (o,c) in kc's tail blocks; read here via
// block-uniform addresses -> s_load into SGPRs.
// grid (320, 16) = (out-channel, batch), block 256 (one thread per 4x4 cell)
__global__ __launch_bounds__(256) void k4_conv2(
    const float* __restrict__ a2, const float* __restrict__ cmb,
    const float* __restrict__ bc2, float* __restrict__ out)
{
    const int o = blockIdx.x, b = blockIdx.y, t = threadIdx.x;
    __shared__ float A[8 * 324];   // (8, 18, 18) zero-halo padded pooled map

    // zero only the 68-cell halo ring per channel (interior fully overwritten)
    for (int i = t; i < 544; i += 256) {
        const int c = i / 68, r = i % 68;
        int y, xx;
        if (r < 18)      { y = 0;      xx = r; }
        else if (r < 36) { y = 17;     xx = r - 18; }
        else if (r < 52) { y = r - 35; xx = 0; }
        else             { y = r - 51; xx = 17; }
        A[c * 324 + y * 18 + xx] = 0.f;
    }
    for (int i = t; i < 2048; i += 256) {
        const int c = i >> 8, y = (i >> 4) & 15, xx = i & 15;
        A[c * 324 + (y + 1) * 18 + (xx + 1)] = a2[(size_t)b * 2048 + i];
    }
    __syncthreads();

    const int cy = t >> 4, cx = t & 15;
    const float bias = bc2[o];
    float acc[3][3];
#pragma unroll
    for (int r = 0; r < 3; ++r)
#pragma unroll
        for (int s = 0; s < 3; ++s) acc[r][s] = bias;

    const float* wp = cmb + o * 200;       // block-uniform -> SGPR
    const float* Abase = &A[cy * 18 + cx];
#pragma unroll
    for (int c = 0; c < 8; ++c) {
        const float C00 = Abase[c * 324 + 0],  C01 = Abase[c * 324 + 1],  C02 = Abase[c * 324 + 2];
        const float C10 = Abase[c * 324 + 18], C11 = Abase[c * 324 + 19], C12 = Abase[c * 324 + 20];
        const float C20 = Abase[c * 324 + 36], C21 = Abase[c * 324 + 37], C22 = Abase[c * 324 + 38];
        const float* w = wp + c * 25;

        acc[0][0] += w[0] * C00 + w[1] * C01 + w[2] * C10 + w[3] * C11;
        acc[0][1] += w[4] * C01 + w[5] * C11;
        acc[0][2] += w[6] * C01 + w[7] * C02 + w[8] * C11 + w[9] * C12;
        acc[1][0] += w[10] * C10 + w[11] * C11;
        acc[1][1] += w[12] * C11;
        acc[1][2] += w[13] * C11 + w[14] * C12;
        acc[2][0] += w[15] * C10 + w[16] * C11 + w[17] * C20 + w[18] * C21;
        acc[2][1] += w[19] * C11 + w[20] * C21;
        acc[2][2] += w[21] * C11 + w[22] * C12 + w[23] * C21 + w[24] * C22;
    }

    const size_t base = ((size_t)(b * 320 + o)) * 4096;
    const int rowmap[4] = {0, 1, 1, 2};
#pragma unroll
    for (int py = 0; py < 4; ++py) {
        const int r = rowmap[py];
        const float4 v = make_float4(acc[r][0], acc[r][1], acc[r][1], acc[r][2]);
        *reinterpret_cast<float4*>(out + base + (cy * 4 + py) * 64 + cx * 4) = v;
    }
}

extern "C" void kernel_launch(void* const* d_in, const int* in_sizes, int n_in,
                              void* d_out, int out_size, void* d_ws, size_t ws_size,
                              hipStream_t stream) {
    const float* x       = (const float*)d_in[0];
    const float* g1      = (const float*)d_in[1];
    const float* b1      = (const float*)d_in[2];
    const float* w_conv1 = (const float*)d_in[3];
    const float* b_conv1 = (const float*)d_in[4];
    const float* ga      = (const float*)d_in[5];
    const float* ba      = (const float*)d_in[6];
    const float* w_qkv   = (const float*)d_in[7];
    const float* b_qkv   = (const float*)d_in[8];
    const float* w_proj  = (const float*)d_in[9];
    const float* b_proj  = (const float*)d_in[10];
    const float* ln_g    = (const float*)d_in[11];
    const float* ln_b    = (const float*)d_in[12];
    const float* w_fc1   = (const float*)d_in[13];
    const float* b_fc1   = (const float*)d_in[14];
    const float* w_fc2   = (const float*)d_in[15];
    const float* b_fc2   = (const float*)d_in[16];
    const float* g2      = (const float*)d_in[17];
    const float* b2      = (const float*)d_in[18];
    const float* w_conv2 = (const float*)d_in[19];
    const float* b_conv2 = (const float*)d_in[20];

    float* pooled = (float*)d_ws;         // 1,310,720 floats (16*320*256)
    float* pcs    = pooled + 1310720;     //    10,240 (5120 float2)
    float* z0p    = pcs + 10240;          //   524,288 (16 b x 16 chunks x 2048)
    float* z0     = z0p + 524288;         //    32,768
    float* a2     = z0 + 32768;           //    32,768
    float* aout   = a2 + 32768;           //    32,768
    float* cmb    = aout + 32768;         //    64,000 (320 o x 8 c x 25 combos)
    float* out = (float*)d_out;

    kp_pool<<<5120, 256, 0, stream>>>(x, pooled, (float2*)pcs);
    kc_gn_conv<<<266, 256, 0, stream>>>(pooled, (const float2*)pcs, g1, b1,
                                        w_conv1, z0p, w_conv2, cmb);
    k3a_attn<<<64, 256, 0, stream>>>(z0p, b_conv1, ga, ba, w_qkv, b_qkv, z0, aout);
    k3c_post<<<16, 256, 0, stream>>>(z0, aout, w_proj, b_proj, ln_g, ln_b,
                                     w_fc1, b_fc1, w_fc2, b_fc2, g2, b2, a2);
    k4_conv2<<<dim3(320, 16), 256, 0, stream>>>(a2, cmb, b_conv2, out);
}